// Round 5
// baseline (506.858 us; speedup 1.0000x reference)
//
#include <hip/hip_runtime.h>

#define NR 131072
#define DD 32
#define KK 64
#define BETA_C 10.0f
#define THREADS 512
#define CSTR 563           // per-cluster stride: 528 tri + 32 sums + 1 cnt + 2 pad
                           // (563 mod 32 = 19, odd -> k*CSTR spreads all 32 banks)
#define CUSED 561          // meaningful floats per cluster
#define CPART (KK * CSTR)  // 36032 floats per partial copy

// ---------------------------------------------------------------------------
// ws layout (float-indexed):
//   [0,64)              fill_g   (atomic accum of softmax p sums)
//   [64,65)             lossAcc
//   [128,33920)         m2low_g  (K x 528 packed lower triangle; reduce out)
//   [33920,35968)       sums_g   (K x 32; reduce out)
//   [35968,36032)       cntf_g   (K floats; reduce out)
//   [36096, +P*CPART)   partials (P copies, atomic-accumulated by fused)
// memsets: first 128 floats + the partial region.
// ---------------------------------------------------------------------------

// Fused kernel: one row per thread (256 blocks x 512 thr == NR exactly).
// Per row: 64 s_load-path dots (R3-validated structure), argmin, softmax,
// 63-shuffle transpose-reduce for filling, then rank-1 update of the winning
// cluster's LDS accumulator (lower triangle + sums + count) via ds_add_f32.
// Block flush: LDS accumulator -> one of P global partial copies (coalesced
// non-returning f32 atomics, address-disjoint within a copy).
__global__ __launch_bounds__(THREADS) void fused_kernel(
    const float* __restrict__ x, const float* __restrict__ centers,
    float* __restrict__ fill_g, float* __restrict__ partials, int P) {
  __shared__ float accS[CPART];   // 144128 B
  __shared__ float cnS[KK];       // ||c_k||^2
  __shared__ float fillW[8][KK];  // per-wave filling results

  const int tid = threadIdx.x;
  const int lane = tid & 63;
  const int wid = tid >> 6;

  for (int e = tid; e < CPART; e += THREADS) accS[e] = 0.f;
  if (tid < KK) {
    float s = 0.f;
    const float* cp = centers + tid * DD;
#pragma unroll
    for (int j = 0; j < DD; ++j) s += cp[j] * cp[j];
    cnS[tid] = s;
  }
  __syncthreads();

  const int row = blockIdx.x * THREADS + tid;

  float xr[DD];  // row in VGPRs, compile-time indexed
  const float4* xp = (const float4*)(x + (size_t)row * DD);
#pragma unroll
  for (int j = 0; j < 8; ++j) {
    const float4 v = xp[j];
    xr[4 * j + 0] = v.x;
    xr[4 * j + 1] = v.y;
    xr[4 * j + 2] = v.z;
    xr[4 * j + 3] = v.w;
  }
  float xx = 0.f;
#pragma unroll
  for (int j = 0; j < DD; ++j) xx += xr[j] * xr[j];

  float pv[KK];  // d2 then p; fully unrolled -> VGPRs
  float best = 3.4e38f;
  int bi = 0;
#pragma unroll
  for (int k = 0; k < KK; ++k) {
    float dot = 0.f;
#pragma unroll
    for (int j = 0; j < DD; ++j)
      dot += xr[j] * centers[k * DD + j];  // uniform addr -> s_load (K$)
    const float d2 = xx - 2.0f * dot + cnS[k];  // same formula as reference
    pv[k] = d2;
    if (d2 < best) { best = d2; bi = k; }  // strict < == first-index ties
  }

  float ssum = 0.f;
#pragma unroll
  for (int k = 0; k < KK; ++k) {
    const float e = __expf(BETA_C * (best - pv[k]));  // arg <= 0
    pv[k] = e;
    ssum += e;
  }
  const float inv = 1.0f / ssum;
#pragma unroll
  for (int k = 0; k < KK; ++k) pv[k] *= inv;

  // 63-shuffle recursive-halving transpose-reduce (R3-validated): lane l ends
  // holding sum over the wave's 64 rows of p[l].
#pragma unroll
  for (int m = 32; m >= 1; m >>= 1) {
    const bool hi = (lane & m) != 0;
#pragma unroll
    for (int i = 0; i < m; ++i) {
      const float send = hi ? pv[i] : pv[i + m];
      const float recv = __shfl_xor(send, m, 64);
      const float keep = hi ? pv[i + m] : pv[i];
      pv[i] = keep + recv;
    }
  }
  fillW[wid][lane] = pv[0];

  // rank-1 update of cluster bi's accumulator: fire-and-forget ds_add_f32.
  float* ak = accS + bi * CSTR;
  unsafeAtomicAdd(&ak[560], 1.0f);  // count
#pragma unroll
  for (int d = 0; d < DD; ++d) unsafeAtomicAdd(&ak[528 + d], xr[d]);  // sums
#pragma unroll
  for (int i = 0; i < DD; ++i) {
#pragma unroll
    for (int j = 0; j <= i; ++j)
      unsafeAtomicAdd(&ak[i * (i + 1) / 2 + j], xr[i] * xr[j]);
  }

  __syncthreads();

  // flush: LDS accumulator -> partial copy (coalesced f32 atomics)
  float* dst = partials + (size_t)(blockIdx.x & (P - 1)) * CPART;
  for (int k = 0; k < KK; ++k)
    for (int r = tid; r < CUSED; r += THREADS)
      unsafeAtomicAdd(&dst[k * CSTR + r], accS[k * CSTR + r]);

  if (tid < KK) {
    float s = 0.f;
#pragma unroll
    for (int w = 0; w < 8; ++w) s += fillW[w][tid];
    atomicAdd(&fill_g[tid], s);
  }
}

// reduce: fold P partial copies into packed outputs. 141 blocks x 256.
__global__ __launch_bounds__(256) void reduce_kernel(
    const float* __restrict__ partials, int P, float* __restrict__ m2low_g,
    float* __restrict__ sums_g, float* __restrict__ cntf_g) {
  const int e = blockIdx.x * 256 + threadIdx.x;
  if (e >= KK * CUSED) return;
  const int k = e / CUSED;
  const int r = e - k * CUSED;
  float s = 0.f;
  for (int c = 0; c < P; ++c) s += partials[(size_t)c * CPART + k * CSTR + r];
  if (r < 528) m2low_g[k * 528 + r] = s;
  else if (r < 560) sums_g[k * DD + (r - 528)] = s;
  else cntf_g[k] = s;
}

// finalize A: one block per cluster; all three loss terms -> atomic scalar.
__global__ __launch_bounds__(256) void finalizeA_kernel(
    const float* __restrict__ fill_g, const float* __restrict__ cntf_g,
    const float* __restrict__ sums_g, const float* __restrict__ m2low_g,
    const float* __restrict__ ft, const float* __restrict__ mt,
    const float* __restrict__ ct, float* __restrict__ lossAcc) {
  __shared__ float meanS[DD];
  __shared__ float wred[4];
  const int t = threadIdx.x;
  const int k = blockIdx.x;

  const float inv = 1.0f / fmaxf(cntf_g[k], 1.0f);
  if (t < DD) meanS[t] = sums_g[k * DD + t] * inv;
  __syncthreads();

  float acc = 0.f;
  if (t < DD) {
    const float d = meanS[t] - mt[k * DD + t];
    acc += d * d * (1.0f / (KK * DD));
  }
  if (t == 0) {
    const float f = fill_g[k] * (1.0f / (float)NR) - ft[k];
    acc += f * f * (1.0f / KK);
  }
  const float* m2k = m2low_g + k * 528;
  const float* ctk = ct + k * (DD * DD);
#pragma unroll
  for (int u = 0; u < 4; ++u) {
    const int e = t + 256 * u;  // coalesced ct reads
    const int i = e >> 5, j = e & 31;
    const int idx = (i >= j) ? (i * (i + 1) / 2 + j) : (j * (j + 1) / 2 + i);
    const float cov = m2k[idx] * inv - meanS[i] * meanS[j];
    const float d = cov - ctk[e];
    acc += d * d * (1.0f / (KK * DD * DD));
  }

  acc += __shfl_xor(acc, 32, 64);
  acc += __shfl_xor(acc, 16, 64);
  acc += __shfl_xor(acc, 8, 64);
  acc += __shfl_xor(acc, 4, 64);
  acc += __shfl_xor(acc, 2, 64);
  acc += __shfl_xor(acc, 1, 64);
  if ((t & 63) == 0) wred[t >> 6] = acc;
  __syncthreads();
  if (t == 0) atomicAdd(lossAcc, wred[0] + wred[1] + wred[2] + wred[3]);
}

__global__ void finalizeB_kernel(const float* __restrict__ lossAcc,
                                 float* __restrict__ out) {
  if (threadIdx.x == 0) out[0] = lossAcc[0];
}

extern "C" void kernel_launch(void* const* d_in, const int* in_sizes, int n_in,
                              void* d_out, int out_size, void* d_ws,
                              size_t ws_size, hipStream_t stream) {
  (void)in_sizes; (void)n_in; (void)out_size;
  const float* x = (const float*)d_in[0];
  const float* centers = (const float*)d_in[1];
  const float* ft = (const float*)d_in[2];
  const float* mt = (const float*)d_in[3];
  const float* ct = (const float*)d_in[4];
  float* out = (float*)d_out;

  float* ws = (float*)d_ws;
  float* fill_g = ws;             // 64
  float* lossAcc = ws + 64;       // 1
  float* m2low_g = ws + 128;      // 33792
  float* sums_g = ws + 33920;     // 2048
  float* cntf_g = ws + 35968;     // 64
  float* partials = ws + 36096;   // P * CPART

  // P: largest power of 2 with room in ws, capped at 32. ws_size is constant
  // across calls -> same work every launch (graph-capture safe). R1 proved
  // ws >= 795 KB, so P >= 4.
  size_t availF = ws_size / 4 > 36096 ? ws_size / 4 - 36096 : 0;
  int P = 1;
  while (P < 32 && (size_t)(P * 2) * CPART <= availF) P *= 2;

  hipMemsetAsync(ws, 0, 128 * sizeof(float), stream);
  hipMemsetAsync(partials, 0, (size_t)P * CPART * sizeof(float), stream);

  fused_kernel<<<NR / THREADS, THREADS, 0, stream>>>(x, centers, fill_g,
                                                     partials, P);
  reduce_kernel<<<(KK * CUSED + 255) / 256, 256, 0, stream>>>(
      partials, P, m2low_g, sums_g, cntf_g);
  finalizeA_kernel<<<KK, 256, 0, stream>>>(fill_g, cntf_g, sums_g, m2low_g, ft,
                                           mt, ct, lossAcc);
  finalizeB_kernel<<<1, 64, 0, stream>>>(lossAcc, out);
}

// Round 6
// 141.300 us; speedup vs baseline: 3.5871x; 3.5871x over previous
//
#include <hip/hip_runtime.h>

#define NR 131072
#define DD 32
#define KK 64
#define BETA_C 10.0f
#define TOTALW 2048
#define MINW 8
#define GRID3 (TOTALW + KK * MINW)  // 2560
#define SUBR 2048
#define TRI(i, j) ((i) * ((i) + 1) / 2 + (j))

// ---------------------------------------------------------------------------
// ws layout (float-indexed):
//   [0,64)         fill_g   (atomic accum of softmax p sums)
//   [64,65)        lossAcc
//   [128,192)      hist_g   (int, per-cluster counts)
//   [192,257)      cumW     (int, 65; planner out)
//   [320,960)      map      (uchar GRID3; planner out: block -> cluster)
//   [960,34752)    m2low_g  (K x 528 packed lower triangle; syrk atomics)
//   [34752,36800)  sums_g   (K x 32; syrk atomics)
//   [36800,69568)  pred8    (uchar, N bytes)
// memset zeroes [0, 36800) floats each launch.
// ---------------------------------------------------------------------------

// phase 1 (R3-validated structure + histogram): one row/thread, centers via
// wave-uniform s_load path, 63-shuffle transpose-reduce for filling.
__global__ __launch_bounds__(256) void phase1_kernel(
    const float* __restrict__ x, const float* __restrict__ centers,
    float* __restrict__ fill_g, int* __restrict__ hist_g,
    unsigned char* __restrict__ pred_g) {
  __shared__ float cnS[KK];       // ||c_k||^2
  __shared__ float fillW[4][KK];  // per-wave filling results
  __shared__ int histS[KK];

  const int tid = threadIdx.x;
  const int lane = tid & 63;
  const int wid = tid >> 6;

  if (tid < KK) {
    float s = 0.f;
    const float* cp = centers + tid * DD;
#pragma unroll
    for (int j = 0; j < DD; ++j) s += cp[j] * cp[j];
    cnS[tid] = s;
    histS[tid] = 0;
  }
  __syncthreads();

  const int row = blockIdx.x * 256 + tid;  // grid == NR/256 exactly

  float xr[DD];  // row in VGPRs, compile-time indexed
  const float4* xp = (const float4*)(x + (size_t)row * DD);
#pragma unroll
  for (int j = 0; j < 8; ++j) {
    const float4 v = xp[j];
    xr[4 * j + 0] = v.x;
    xr[4 * j + 1] = v.y;
    xr[4 * j + 2] = v.z;
    xr[4 * j + 3] = v.w;
  }
  float xx = 0.f;
#pragma unroll
  for (int j = 0; j < DD; ++j) xx += xr[j] * xr[j];

  float pv[KK];  // d2, then p; fully unrolled -> VGPRs
  float best = 3.4e38f;
  int bi = 0;
#pragma unroll
  for (int k = 0; k < KK; ++k) {
    float dot = 0.f;
#pragma unroll
    for (int j = 0; j < DD; ++j)
      dot += xr[j] * centers[k * DD + j];  // uniform addr -> s_load (K$)
    const float d2 = xx - 2.0f * dot + cnS[k];  // same formula as reference
    pv[k] = d2;
    if (d2 < best) { best = d2; bi = k; }  // strict < == first-index ties
  }
  pred_g[row] = (unsigned char)bi;
  atomicAdd(&histS[bi], 1);

  float ssum = 0.f;
#pragma unroll
  for (int k = 0; k < KK; ++k) {
    const float e = __expf(BETA_C * (best - pv[k]));  // arg <= 0
    pv[k] = e;
    ssum += e;
  }
  const float inv = 1.0f / ssum;
#pragma unroll
  for (int k = 0; k < KK; ++k) pv[k] *= inv;

  // 63-shuffle recursive-halving transpose-reduce (R3-validated)
#pragma unroll
  for (int m = 32; m >= 1; m >>= 1) {
    const bool hi = (lane & m) != 0;
#pragma unroll
    for (int i = 0; i < m; ++i) {
      const float send = hi ? pv[i] : pv[i + m];
      const float recv = __shfl_xor(send, m, 64);
      const float keep = hi ? pv[i + m] : pv[i];
      pv[i] = keep + recv;
    }
  }
  fillW[wid][lane] = pv[0];
  __syncthreads();
  if (tid < KK) {
    atomicAdd(&fill_g[tid],
              fillW[0][tid] + fillW[1][tid] + fillW[2][tid] + fillW[3][tid]);
    if (histS[tid]) atomicAdd(&hist_g[tid], histS[tid]);
  }
}

// planner: count-proportional worker assignment. W_k = max(MINW, TOTALW*c/N);
// writes exclusive cumW and a block->cluster map (255 = idle block).
__global__ void planner_kernel(const int* __restrict__ hist_g,
                               int* __restrict__ cumW,
                               unsigned char* __restrict__ map) {
  __shared__ int cw[KK + 1];
  const int t = threadIdx.x;  // 64
  if (t == 0) {
    int acc = 0;
    for (int k = 0; k < KK; ++k) {
      cw[k] = acc;
      int w = (TOTALW * hist_g[k]) / NR;
      if (w < MINW) w = MINW;
      acc += w;
    }
    cw[KK] = acc;
  }
  __syncthreads();
  cumW[t] = cw[t];
  if (t == 0) cumW[KK] = cw[KK];
  for (int b = cw[t]; b < cw[t + 1]; ++b) map[b] = (unsigned char)t;
  const int total = cw[KK];  // <= GRID3 by construction
  for (int b = total + t; b < GRID3; b += 64) map[b] = 255;
}

// syrk: block = (cluster k, worker wi) handles row range [r0,r1). Scan with
// ballot compaction (uniform trip counts -> ballots always full-wave), gather
// 64-row tiles TRANSPOSED into xsT[d][r] (stride 68: 16B-aligned, A-reads
// conflict-free, B-reads 2-way=free), compute 2x2 tiles with ds_read_b128
// over 4-row groups (4x fewer LDS instrs than R3). Lower-triangle flush.
__global__ __launch_bounds__(256) void syrk_kernel(
    const float* __restrict__ x, const unsigned char* __restrict__ pred_g,
    const int* __restrict__ cumW, const unsigned char* __restrict__ map,
    float* __restrict__ m2low_g, float* __restrict__ sums_g) {
  __shared__ unsigned short idxList[SUBR];  // 4 KB
  __shared__ float xsT[DD][68];             // transposed tile, 8.7 KB
  __shared__ int cntS;

  const int bid = blockIdx.x;
  const int k = map[bid];
  if (k == 255) return;
  const int tid = threadIdx.x;
  const int lane = tid & 63;
  const int w0 = cumW[k], w1 = cumW[k + 1];
  const int W = w1 - w0;
  const int wi = bid - w0;
  const int r0 = (int)(((long long)NR * wi) / W) & ~3;
  const int r1 =
      (wi == W - 1) ? NR : ((int)(((long long)NR * (wi + 1)) / W) & ~3);

  const int ti = tid >> 4, tj = tid & 15;
  const int i0 = ti, i1 = ti + 16, j0 = tj, j1 = tj + 16;
  float c00 = 0.f, c10 = 0.f, c11 = 0.f, sd0 = 0.f, sd1 = 0.f;

  for (int sub = r0; sub < r1; sub += SUBR) {
    const int send = min(sub + SUBR, r1);
    __syncthreads();  // previous sub's idxList readers done
    if (tid == 0) cntS = 0;
    __syncthreads();
    for (int bb = sub; bb < send; bb += 1024) {  // uniform trip count
      const int b = bb + tid * 4;
      const bool inr = b < send;  // 4-aligned bounds -> whole uchar4 in/out
      uchar4 p4 = make_uchar4(255, 255, 255, 255);
      if (inr) p4 = *(const uchar4*)(pred_g + b);
      const int pr[4] = {p4.x, p4.y, p4.z, p4.w};
#pragma unroll
      for (int c = 0; c < 4; ++c) {
        const bool match = (pr[c] == k);
        const unsigned long long mask = __ballot(match);
        const int tot = __popcll(mask);
        const int pre = __builtin_amdgcn_mbcnt_hi(
            (unsigned)(mask >> 32),
            __builtin_amdgcn_mbcnt_lo((unsigned)mask, 0));
        int base = 0;
        if (lane == 0 && tot) base = atomicAdd(&cntS, tot);
        base = __shfl(base, 0, 64);
        if (match) idxList[base + pre] = (unsigned short)(b + c - sub);
      }
    }
    __syncthreads();
    const int m = cntS;  // uniform; m <= SUBR by construction
    for (int off = 0; off < m; off += 64) {
      const int cnt = min(64, m - off);
      const int cnt4 = (cnt + 3) & ~3;
      __syncthreads();  // previous tile's readers done before overwrite
      for (int e = tid; e < cnt * DD; e += 256) {
        const int r = sub + (int)idxList[off + (e >> 5)];
        xsT[e & 31][e >> 5] = x[(size_t)r * DD + (e & 31)];  // coalesced read
      }
      for (int e = cnt * DD + tid; e < cnt4 * DD; e += 256)
        xsT[e & 31][e >> 5] = 0.f;  // zero-pad rows to multiple of 4
      __syncthreads();
      for (int g = 0; g < (cnt4 >> 2); ++g) {
        const float4 A0 = *(const float4*)&xsT[i0][4 * g];
        const float4 A1 = *(const float4*)&xsT[i1][4 * g];
        const float4 B0 = *(const float4*)&xsT[j0][4 * g];
        const float4 B1 = *(const float4*)&xsT[j1][4 * g];
        c00 += A0.x * B0.x + A0.y * B0.y + A0.z * B0.z + A0.w * B0.w;
        c10 += A1.x * B0.x + A1.y * B0.y + A1.z * B0.z + A1.w * B0.w;
        c11 += A1.x * B1.x + A1.y * B1.y + A1.z * B1.z + A1.w * B1.w;
        if (tj == 0) {  // sums from already-loaded registers (no extra LDS)
          sd0 += A0.x + A0.y + A0.z + A0.w;
          sd1 += A1.x + A1.y + A1.z + A1.w;
        }
      }
    }
  }

  // lower-triangle flush (R3-validated fold): (i1,j0) always lower-tri;
  // (i0,j0)/(i1,j1) exactly once via tj<=ti.
  float* m2k = m2low_g + k * 528;
  atomicAdd(&m2k[TRI(i1, j0)], c10);
  if (tj <= ti) {
    atomicAdd(&m2k[TRI(i0, j0)], c00);
    atomicAdd(&m2k[TRI(i1, j1)], c11);
  }
  if (tj == 0) {
    atomicAdd(&sums_g[k * DD + i0], sd0);
    atomicAdd(&sums_g[k * DD + i1], sd1);
  }
}

// finalize A (R5-validated tri-packed form): one block per cluster.
__global__ __launch_bounds__(256) void finalizeA_kernel(
    const float* __restrict__ fill_g, const int* __restrict__ hist_g,
    const float* __restrict__ sums_g, const float* __restrict__ m2low_g,
    const float* __restrict__ ft, const float* __restrict__ mt,
    const float* __restrict__ ct, float* __restrict__ lossAcc) {
  __shared__ float meanS[DD];
  __shared__ float wred[4];
  const int t = threadIdx.x;
  const int k = blockIdx.x;

  const float inv = 1.0f / fmaxf((float)hist_g[k], 1.0f);
  if (t < DD) meanS[t] = sums_g[k * DD + t] * inv;
  __syncthreads();

  float acc = 0.f;
  if (t < DD) {
    const float d = meanS[t] - mt[k * DD + t];
    acc += d * d * (1.0f / (KK * DD));
  }
  if (t == 0) {
    const float f = fill_g[k] * (1.0f / (float)NR) - ft[k];
    acc += f * f * (1.0f / KK);
  }
  const float* m2k = m2low_g + k * 528;
  const float* ctk = ct + k * (DD * DD);
#pragma unroll
  for (int u = 0; u < 4; ++u) {
    const int e = t + 256 * u;  // coalesced ct reads
    const int i = e >> 5, j = e & 31;
    const int idx = (i >= j) ? TRI(i, j) : TRI(j, i);
    const float cov = m2k[idx] * inv - meanS[i] * meanS[j];
    const float d = cov - ctk[e];
    acc += d * d * (1.0f / (KK * DD * DD));
  }

  acc += __shfl_xor(acc, 32, 64);
  acc += __shfl_xor(acc, 16, 64);
  acc += __shfl_xor(acc, 8, 64);
  acc += __shfl_xor(acc, 4, 64);
  acc += __shfl_xor(acc, 2, 64);
  acc += __shfl_xor(acc, 1, 64);
  if ((t & 63) == 0) wred[t >> 6] = acc;
  __syncthreads();
  if (t == 0) atomicAdd(lossAcc, wred[0] + wred[1] + wred[2] + wred[3]);
}

__global__ void finalizeB_kernel(const float* __restrict__ lossAcc,
                                 float* __restrict__ out) {
  if (threadIdx.x == 0) out[0] = lossAcc[0];
}

extern "C" void kernel_launch(void* const* d_in, const int* in_sizes, int n_in,
                              void* d_out, int out_size, void* d_ws,
                              size_t ws_size, hipStream_t stream) {
  (void)in_sizes; (void)n_in; (void)out_size; (void)ws_size;
  const float* x = (const float*)d_in[0];
  const float* centers = (const float*)d_in[1];
  const float* ft = (const float*)d_in[2];
  const float* mt = (const float*)d_in[3];
  const float* ct = (const float*)d_in[4];
  float* out = (float*)d_out;

  float* ws = (float*)d_ws;
  float* fill_g = ws;                                   // 64
  float* lossAcc = ws + 64;                             // 1
  int* hist_g = (int*)(ws + 128);                       // 64
  int* cumW = (int*)(ws + 192);                         // 65
  unsigned char* map = (unsigned char*)(ws + 320);      // GRID3 bytes
  float* m2low_g = ws + 960;                            // 33792
  float* sums_g = ws + 34752;                           // 2048
  unsigned char* pred8 = (unsigned char*)(ws + 36800);  // N bytes

  hipMemsetAsync(d_ws, 0, (size_t)36800 * sizeof(float), stream);

  phase1_kernel<<<NR / 256, 256, 0, stream>>>(x, centers, fill_g, hist_g,
                                              pred8);
  planner_kernel<<<1, 64, 0, stream>>>(hist_g, cumW, map);
  syrk_kernel<<<GRID3, 256, 0, stream>>>(x, pred8, cumW, map, m2low_g, sums_g);
  finalizeA_kernel<<<KK, 256, 0, stream>>>(fill_g, hist_g, sums_g, m2low_g, ft,
                                           mt, ct, lossAcc);
  finalizeB_kernel<<<1, 64, 0, stream>>>(lossAcc, out);
}